// Round 8
// baseline (225.816 us; speedup 1.0000x reference)
//
#include <hip/hip_runtime.h>

// HaloAttention. B=2, H=W=128, C=128, NH=4, hd=32, WS=16, HS=8, WSH=32.
// R8: R6 key-split structure with the spill fixed: ks-phased S tiles keep the
// live set ~116 regs under the 128 cap of __launch_bounds__(512,4) (2 blk/CU,
// 16 waves/CU). XCD-aware window swizzle (4x4-window tile per XCD -> K/V
// L2-resident). Single-barrier Vt staging: chunk c+1 global loads held in
// regs across chunk-c compute. prep = fused pack_w + bias_frag.

typedef unsigned short ushort_t;
typedef __attribute__((ext_vector_type(8))) short bf16x8;
typedef __attribute__((ext_vector_type(4))) float floatx4;

#define NHEADS 4
#define BTBL 2209          // 47*47 bias table rows
#define PK 40              // P stride (bf16): 32 keys + 8 pad
#define VK 72              // Vt stride (bf16): 64 keys + 8 pad
// 2^-1.5 * log2(e)  (q scale folded with exp2-domain conversion)
#define QS_LOG2E 0.2550348635f
#define LOG2E 1.4426950408889634f

#if __has_builtin(__builtin_amdgcn_exp2f)
#define EXP2F(x) __builtin_amdgcn_exp2f(x)
#else
#define EXP2F(x) __expf((x) * 0.6931471805599453f)
#endif

__device__ __forceinline__ int reflect_idx(int p) {
    p = (p < 0) ? -p : p;
    p = (p > 127) ? 254 - p : p;
    return p;
}

// fp32 -> bf16 bits, RNE
__device__ __forceinline__ unsigned f2b(float x) {
    unsigned u = __float_as_uint(x);
    return (u + 0x7fffu + ((u >> 16) & 1u)) >> 16;
}

// ---------------------------------------------------------------------------
// prep: blocks [0,4096) build bf16 bias fragments (log2e domain);
// blocks [4096,4353) pack weights/biases.
__global__ __launch_bounds__(256) void prep(
    const float* __restrict__ bt,
    const float* __restrict__ Wq, const float* __restrict__ Wk,
    const float* __restrict__ Wv, const float* __restrict__ Wp,
    const float* __restrict__ bq, const float* __restrict__ bk,
    const float* __restrict__ bv, const float* __restrict__ bp,
    ushort_t* __restrict__ bf,
    ushort_t* __restrict__ Wqkv, ushort_t* __restrict__ Wpb,
    float* __restrict__ bqkv, float* __restrict__ bpb)
{
    const int bx = blockIdx.x;
    if (bx < 4096) {
        int idx = bx * 256 + threadIdx.x;       // 1,048,576 entries
        int reg  = idx & 3;
        int lane = (idx >> 2) & 63;
        int qt   = (idx >> 8) & 15;
        int kt   = (idx >> 12) & 63;
        int h    = idx >> 18;                   // 0..3
        int key  = kt * 16 + ((lane >> 4) << 2) + reg;
        int q    = qt * 16 + (lane & 15);
        int kr = key >> 5, kc = key & 31;
        int bidx = ((q >> 5) + 31 - kr) * 47 + (q & 31) - kc + 23;
        if (bidx < 0) bidx += BTBL;
        bf[idx] = (ushort_t)f2b(bt[bidx * NHEADS + h] * LOG2E);
    } else {
        int idx = (bx - 4096) * 256 + threadIdx.x;
        if (idx < 16384)       Wqkv[idx] = (ushort_t)f2b(Wq[idx]);
        else if (idx < 32768)  Wqkv[idx] = (ushort_t)f2b(Wk[idx - 16384]);
        else if (idx < 49152)  Wqkv[idx] = (ushort_t)f2b(Wv[idx - 32768]);
        else if (idx < 65536)  Wpb[idx - 49152] = (ushort_t)f2b(Wp[idx - 49152]);
        else {
            int e = idx - 65536;
            for (int k = e; k < 512; k += 256) {
                if (k < 128)      bqkv[k] = bq[k];
                else if (k < 256) bqkv[k] = bk[k - 128];
                else if (k < 384) bqkv[k] = bv[k - 256];
                else              bpb[k - 384] = bp[k - 384];
            }
        }
    }
}

// ---------------------------------------------------------------------------
// QKV GEMM, 64-row tiles, grid (512, 3). Q block (nb==0) scaled.
__global__ __launch_bounds__(256) void gemm_qkv(
    const float* __restrict__ X, const ushort_t* __restrict__ W,
    const float* __restrict__ bias, ushort_t* __restrict__ Y)
{
    __shared__ ushort_t Xs[64 * 136];

    const int t    = threadIdx.x;
    const int wq   = t >> 6;
    const int lane = t & 63;
    const int quad = lane >> 4;
    const int l15  = lane & 15;
    const int m0   = blockIdx.x * 64;
    const int nb   = blockIdx.y;
    const float sc = (nb == 0) ? QS_LOG2E : 1.0f;

    #pragma unroll
    for (int i = 0; i < 8; ++i) {
        int s = t + i * 256;
        int row = s >> 5, c4 = s & 31;
        float4 v = *(const float4*)&X[(size_t)(m0 + row) * 128 + c4 * 4];
        uint2 pk;
        pk.x = f2b(v.x) | (f2b(v.y) << 16);
        pk.y = f2b(v.z) | (f2b(v.w) << 16);
        *(uint2*)&Xs[row * 136 + c4 * 4] = pk;
    }
    __syncthreads();

    floatx4 acc[8];
    #pragma unroll
    for (int nt = 0; nt < 8; ++nt)
        acc[nt] = (floatx4)(bias[nb * 128 + nt * 16 + l15]);

    #pragma unroll
    for (int kc = 0; kc < 4; ++kc) {
        bf16x8 af = *(const bf16x8*)&Xs[(wq * 16 + l15) * 136 + kc * 32 + quad * 8];
        #pragma unroll
        for (int nt = 0; nt < 8; ++nt) {
            bf16x8 bfr = *(const bf16x8*)&W[(size_t)(nb * 128 + nt * 16 + l15) * 128 + kc * 32 + quad * 8];
            acc[nt] = __builtin_amdgcn_mfma_f32_16x16x32_bf16(af, bfr, acc[nt], 0, 0, 0);
        }
    }

    #pragma unroll
    for (int r = 0; r < 4; ++r) {
        int m = m0 + wq * 16 + quad * 4 + r;
        #pragma unroll
        for (int nt = 0; nt < 8; ++nt)
            Y[(size_t)m * 384 + nb * 128 + nt * 16 + l15] = (ushort_t)f2b(acc[nt][r] * sc);
    }
}

// ---------------------------------------------------------------------------
// Projection GEMM, 64-row tiles, grid (512). bf16 in, fp32 out.
__global__ __launch_bounds__(256) void gemm_proj(
    const ushort_t* __restrict__ X, const ushort_t* __restrict__ W,
    const float* __restrict__ bias, float* __restrict__ Y)
{
    __shared__ ushort_t Xs[64 * 136];

    const int t    = threadIdx.x;
    const int wq   = t >> 6;
    const int lane = t & 63;
    const int quad = lane >> 4;
    const int l15  = lane & 15;
    const int m0   = blockIdx.x * 64;

    #pragma unroll
    for (int i = 0; i < 4; ++i) {
        int s = t + i * 256;
        int row = s >> 4, c8 = s & 15;
        *(int4*)&Xs[row * 136 + c8 * 8] = *(const int4*)&X[(size_t)(m0 + row) * 128 + c8 * 8];
    }
    __syncthreads();

    floatx4 acc[8];
    #pragma unroll
    for (int nt = 0; nt < 8; ++nt)
        acc[nt] = (floatx4)(bias[nt * 16 + l15]);

    #pragma unroll
    for (int kc = 0; kc < 4; ++kc) {
        bf16x8 af = *(const bf16x8*)&Xs[(wq * 16 + l15) * 136 + kc * 32 + quad * 8];
        #pragma unroll
        for (int nt = 0; nt < 8; ++nt) {
            bf16x8 bfr = *(const bf16x8*)&W[(size_t)(nt * 16 + l15) * 128 + kc * 32 + quad * 8];
            acc[nt] = __builtin_amdgcn_mfma_f32_16x16x32_bf16(af, bfr, acc[nt], 0, 0, 0);
        }
    }

    #pragma unroll
    for (int r = 0; r < 4; ++r) {
        int m = m0 + wq * 16 + quad * 4 + r;
        #pragma unroll
        for (int nt = 0; nt < 8; ++nt)
            Y[(size_t)m * 128 + nt * 16 + l15] = acc[nt][r];
    }
}

// ---------------------------------------------------------------------------
// Attention: block = (win, head), 512 threads = 8 waves (khalf*4 + wq).
// Wave: 64 queries (4 q-tiles) x 512 keys (its half). Additive partial
// combine. XCD swizzle: x&7 selects a 4x4-window spatial tile -> one XCD.
__global__ __launch_bounds__(512, 4) void halo_attn(
    const ushort_t* __restrict__ QKV,   // [32768][384] bf16 (Q pre-scaled)
    const ushort_t* __restrict__ biasf, // bf16 fragment bias (log2e domain)
    ushort_t* __restrict__ O)           // [32768][128] bf16
{
    __shared__ ushort_t P_lds[8 * 64 * PK];      // 40960 B (also combine buf)
    __shared__ ushort_t Vt_lds[4 * 32 * VK];     // 18432 B: [khalf][buf][32][VK]

    const int t     = threadIdx.x;
    const int wave  = t >> 6;
    const int khalf = wave >> 2;
    const int wq    = wave & 3;
    const int lane  = t & 63;
    const int quad  = lane >> 4;
    const int l15   = lane & 15;

    // XCD-aware decode: tile id = x&7 (one per XCD), 16 windows per tile.
    const int x  = blockIdx.x;
    const int tt = x & 7;
    const int w  = x >> 3;
    const int b  = tt >> 2;
    const int wh = ((tt >> 1) & 1) * 4 + (w >> 2);
    const int ww = (tt & 1) * 4 + (w & 3);
    const int head = blockIdx.y;

    // Q B-fragments (persistent)
    bf16x8 qf[4];
    int qpix[4];
    #pragma unroll
    for (int qt = 0; qt < 4; ++qt) {
        int q_abs = wq * 64 + qt * 16 + l15;
        int gy = wh * 16 + (q_abs >> 4), gx = ww * 16 + (q_abs & 15);
        int pix = (b * 128 + gy) * 128 + gx;
        qpix[qt] = pix;
        qf[qt] = *(const bf16x8*)(QKV + (size_t)pix * 384 + head * 32 + quad * 8);
    }

    floatx4 Oa[2][4];
    #pragma unroll
    for (int dt = 0; dt < 2; ++dt)
        #pragma unroll
        for (int qt = 0; qt < 4; ++qt)
            Oa[dt][qt] = (floatx4)0.f;
    float l[4] = {0.f, 0.f, 0.f, 0.f};

    ushort_t* Pw = P_lds + wave * 64 * PK;
    const int key_local = wq * 16 + l15;

    // prefetch V stage for chunk 0 into regs
    int4 hold;
    {
        int key = (khalf * 8 + 0) * 64 + key_local;
        int ky = reflect_idx(wh * 16 + (key >> 5) - 8);
        int kx = reflect_idx(ww * 16 + (key & 31) - 8);
        int pixv = (b * 128 + ky) * 128 + kx;
        hold = *(const int4*)(QKV + (size_t)pixv * 384 + 256 + head * 32 + quad * 8);
    }

    for (int c = 0; c < 8; ++c) {
        const int kc_abs = khalf * 8 + c;
        ushort_t* Vtw = Vt_lds + (khalf * 2 + (c & 1)) * 32 * VK;

        // write held V chunk into this chunk's buffer
        {
            const ushort_t* vs = (const ushort_t*)&hold;
            #pragma unroll
            for (int i = 0; i < 8; ++i)
                Vtw[(quad * 8 + i) * VK + key_local] = vs[i];
        }
        __syncthreads();

        // issue next chunk's global V load (held in regs across compute)
        if (c < 7) {
            int key = (kc_abs + 1) * 64 + key_local;
            int ky = reflect_idx(wh * 16 + (key >> 5) - 8);
            int kx = reflect_idx(ww * 16 + (key & 31) - 8);
            int pixv = (b * 128 + ky) * 128 + kx;
            hold = *(const int4*)(QKV + (size_t)pixv * 384 + 256 + head * 32 + quad * 8);
        }

        // ---- compute in two 32-key phases (keeps S live-set at 32 regs) ----
        #pragma unroll
        for (int ks = 0; ks < 2; ++ks) {
            bf16x8 kf[2];
            #pragma unroll
            for (int kh = 0; kh < 2; ++kh) {
                int key = kc_abs * 64 + (ks * 2 + kh) * 16 + l15;
                int ky = reflect_idx(wh * 16 + (key >> 5) - 8);
                int kx = reflect_idx(ww * 16 + (key & 31) - 8);
                int pixk = (b * 128 + ky) * 128 + kx;
                kf[kh] = *(const bf16x8*)(QKV + (size_t)pixk * 384 + 128 + head * 32 + quad * 8);
            }

            floatx4 S[2][4];
            #pragma unroll
            for (int kh = 0; kh < 2; ++kh) {
                int kt_abs = kc_abs * 4 + ks * 2 + kh;
                #pragma unroll
                for (int qt = 0; qt < 4; ++qt) {
                    int qt_abs = wq * 4 + qt;
                    uint2 pk = *(const uint2*)(biasf +
                        ((((size_t)head * 64 + kt_abs) * 16 + qt_abs) * 64 + lane) * 4);
                    S[kh][qt][0] = __uint_as_float(pk.x << 16);
                    S[kh][qt][1] = __uint_as_float(pk.x & 0xffff0000u);
                    S[kh][qt][2] = __uint_as_float(pk.y << 16);
                    S[kh][qt][3] = __uint_as_float(pk.y & 0xffff0000u);
                }
            }
            #pragma unroll
            for (int kh = 0; kh < 2; ++kh)
                #pragma unroll
                for (int qt = 0; qt < 4; ++qt)
                    S[kh][qt] = __builtin_amdgcn_mfma_f32_16x16x32_bf16(kf[kh], qf[qt], S[kh][qt], 0, 0, 0);

            // exp2 + partial l + pack P for this 32-key group
            #pragma unroll
            for (int qt = 0; qt < 4; ++qt) {
                float ls = 0.f;
                #pragma unroll
                for (int kh = 0; kh < 2; ++kh)
                    #pragma unroll
                    for (int r = 0; r < 4; ++r) {
                        float p = EXP2F(S[kh][qt][r]);
                        S[kh][qt][r] = p;
                        ls += p;
                    }
                l[qt] += ls;
                #pragma unroll
                for (int kh = 0; kh < 2; ++kh) {
                    uint2 pk;
                    pk.x = __builtin_amdgcn_perm(__float_as_uint(S[kh][qt][1]),
                                                 __float_as_uint(S[kh][qt][0]), 0x07060302u);
                    pk.y = __builtin_amdgcn_perm(__float_as_uint(S[kh][qt][3]),
                                                 __float_as_uint(S[kh][qt][2]), 0x07060302u);
                    *(uint2*)&Pw[(qt * 16 + l15) * PK + kh * 16 + quad * 4] = pk;
                }
            }

            // PV for this 32-key group
            bf16x8 vf[2];
            #pragma unroll
            for (int dt = 0; dt < 2; ++dt)
                vf[dt] = *(const bf16x8*)&Vtw[(dt * 16 + l15) * VK + ks * 32 + quad * 8];
            #pragma unroll
            for (int qt = 0; qt < 4; ++qt) {
                bf16x8 pf = *(const bf16x8*)&Pw[(qt * 16 + l15) * PK + quad * 8];
                #pragma unroll
                for (int dt = 0; dt < 2; ++dt)
                    Oa[dt][qt] = __builtin_amdgcn_mfma_f32_16x16x32_bf16(vf[dt], pf, Oa[dt][qt], 0, 0, 0);
            }
        }
    }

    // ---- combine key-halves: khalf1 writes partials, khalf0 sums+stores ----
    __syncthreads();
    float* slot = (float*)P_lds + (size_t)(wq * 64 + lane) * 40;
    if (khalf == 1) {
        #pragma unroll
        for (int dt = 0; dt < 2; ++dt)
            #pragma unroll
            for (int qt = 0; qt < 4; ++qt)
                *(floatx4*)(slot + (dt * 4 + qt) * 4) = Oa[dt][qt];
        floatx4 lv = {l[0], l[1], l[2], l[3]};
        *(floatx4*)(slot + 32) = lv;
    }
    __syncthreads();
    if (khalf == 0) {
        #pragma unroll
        for (int dt = 0; dt < 2; ++dt)
            #pragma unroll
            for (int qt = 0; qt < 4; ++qt)
                Oa[dt][qt] += *(const floatx4*)(slot + (dt * 4 + qt) * 4);
        floatx4 lv = *(const floatx4*)(slot + 32);
        #pragma unroll
        for (int qt = 0; qt < 4; ++qt) {
            float lq = l[qt] + lv[qt];
            lq += __shfl_xor(lq, 16);
            lq += __shfl_xor(lq, 32);
            float inv = 1.0f / lq;
            #pragma unroll
            for (int dt = 0; dt < 2; ++dt) {
                uint2 pk;
                pk.x = f2b(Oa[dt][qt][0] * inv) | (f2b(Oa[dt][qt][1] * inv) << 16);
                pk.y = f2b(Oa[dt][qt][2] * inv) | (f2b(Oa[dt][qt][3] * inv) << 16);
                *(uint2*)(O + (size_t)qpix[qt] * 128 + head * 32 + dt * 16 + quad * 4) = pk;
            }
        }
    }
}

// ---------------------------------------------------------------------------
extern "C" void kernel_launch(void* const* d_in, const int* in_sizes, int n_in,
                              void* d_out, int out_size, void* d_ws, size_t ws_size,
                              hipStream_t stream)
{
    const float* x          = (const float*)d_in[0];
    const float* Wq         = (const float*)d_in[1];
    const float* bq         = (const float*)d_in[2];
    const float* Wk         = (const float*)d_in[3];
    const float* bk         = (const float*)d_in[4];
    const float* Wv         = (const float*)d_in[5];
    const float* bv         = (const float*)d_in[6];
    const float* Wp         = (const float*)d_in[7];
    const float* bp         = (const float*)d_in[8];
    const float* bias_table = (const float*)d_in[9];
    float* out = (float*)d_out;

    char* ws = (char*)d_ws;
    ushort_t* Wqkv  = (ushort_t*)(ws);                    // 98304 B
    ushort_t* Wpb   = (ushort_t*)(ws + 98304);            // 32768 B
    float*    bqkv  = (float*)   (ws + 131072);           // 1536 B
    float*    bpb   = (float*)   (ws + 132608);           // 512 B
    ushort_t* QKV   = (ushort_t*)(ws + 133120);           // 25165824 B
    ushort_t* Ob    = (ushort_t*)(ws + 25298944);         // 8388608 B
    ushort_t* biasf = (ushort_t*)(ws + 33687552);         // 2097152 B

    prep<<<dim3(4353), dim3(256), 0, stream>>>(bias_table, Wq, Wk, Wv, Wp,
                                               bq, bk, bv, bp,
                                               biasf, Wqkv, Wpb, bqkv, bpb);
    gemm_qkv<<<dim3(512, 3), dim3(256), 0, stream>>>(x, Wqkv, bqkv, QKV);
    halo_attn<<<dim3(128, NHEADS), dim3(512), 0, stream>>>(QKV, biasf, Ob);
    gemm_proj<<<dim3(512), dim3(256), 0, stream>>>(Ob, Wpb, bpb, out);
}

// Round 9
// 188.442 us; speedup vs baseline: 1.1983x; 1.1983x over previous
//
#include <hip/hip_runtime.h>

// HaloAttention. B=2, H=W=128, C=128, NH=4, hd=32, WS=16, HS=8, WSH=32.
// R9: R5's barrier-free attention (4 independent waves, per-wave Vt+P, no
// __syncthreads, natural ~92-reg allocation) with LDS cut to 38.9 KB via a
// phased 32-key P buffer -> 4 blocks/CU (16 waves/CU, 2x R5's TLP).
// XCD window-tile swizzle for K/V L2 residency. GEMMs/prep as R8.

typedef unsigned short ushort_t;
typedef __attribute__((ext_vector_type(8))) short bf16x8;
typedef __attribute__((ext_vector_type(4))) float floatx4;

#define NHEADS 4
#define BTBL 2209          // 47*47 bias table rows
#define PK 40              // P stride (bf16): 32 keys + 8 pad
#define VK 72              // Vt stride (bf16): 64 keys + 8 pad
// 2^-1.5 * log2(e)  (q scale folded with exp2-domain conversion)
#define QS_LOG2E 0.2550348635f
#define LOG2E 1.4426950408889634f

#if __has_builtin(__builtin_amdgcn_exp2f)
#define EXP2F(x) __builtin_amdgcn_exp2f(x)
#else
#define EXP2F(x) __expf((x) * 0.6931471805599453f)
#endif

__device__ __forceinline__ int reflect_idx(int p) {
    p = (p < 0) ? -p : p;
    p = (p > 127) ? 254 - p : p;
    return p;
}

// fp32 -> bf16 bits, RNE
__device__ __forceinline__ unsigned f2b(float x) {
    unsigned u = __float_as_uint(x);
    return (u + 0x7fffu + ((u >> 16) & 1u)) >> 16;
}

// ---------------------------------------------------------------------------
// prep: blocks [0,4096) build bf16 bias fragments (log2e domain);
// blocks [4096,4353) pack weights/biases.
__global__ __launch_bounds__(256) void prep(
    const float* __restrict__ bt,
    const float* __restrict__ Wq, const float* __restrict__ Wk,
    const float* __restrict__ Wv, const float* __restrict__ Wp,
    const float* __restrict__ bq, const float* __restrict__ bk,
    const float* __restrict__ bv, const float* __restrict__ bp,
    ushort_t* __restrict__ bf,
    ushort_t* __restrict__ Wqkv, ushort_t* __restrict__ Wpb,
    float* __restrict__ bqkv, float* __restrict__ bpb)
{
    const int bx = blockIdx.x;
    if (bx < 4096) {
        int idx = bx * 256 + threadIdx.x;       // 1,048,576 entries
        int reg  = idx & 3;
        int lane = (idx >> 2) & 63;
        int qt   = (idx >> 8) & 15;
        int kt   = (idx >> 12) & 63;
        int h    = idx >> 18;                   // 0..3
        int key  = kt * 16 + ((lane >> 4) << 2) + reg;
        int q    = qt * 16 + (lane & 15);
        int kr = key >> 5, kc = key & 31;
        int bidx = ((q >> 5) + 31 - kr) * 47 + (q & 31) - kc + 23;
        if (bidx < 0) bidx += BTBL;
        bf[idx] = (ushort_t)f2b(bt[bidx * NHEADS + h] * LOG2E);
    } else {
        int idx = (bx - 4096) * 256 + threadIdx.x;
        if (idx < 16384)       Wqkv[idx] = (ushort_t)f2b(Wq[idx]);
        else if (idx < 32768)  Wqkv[idx] = (ushort_t)f2b(Wk[idx - 16384]);
        else if (idx < 49152)  Wqkv[idx] = (ushort_t)f2b(Wv[idx - 32768]);
        else if (idx < 65536)  Wpb[idx - 49152] = (ushort_t)f2b(Wp[idx - 49152]);
        else {
            int e = idx - 65536;
            for (int k = e; k < 512; k += 256) {
                if (k < 128)      bqkv[k] = bq[k];
                else if (k < 256) bqkv[k] = bk[k - 128];
                else if (k < 384) bqkv[k] = bv[k - 256];
                else              bpb[k - 384] = bp[k - 384];
            }
        }
    }
}

// ---------------------------------------------------------------------------
// QKV GEMM, 64-row tiles, grid (512, 3). Q block (nb==0) scaled.
__global__ __launch_bounds__(256) void gemm_qkv(
    const float* __restrict__ X, const ushort_t* __restrict__ W,
    const float* __restrict__ bias, ushort_t* __restrict__ Y)
{
    __shared__ ushort_t Xs[64 * 136];

    const int t    = threadIdx.x;
    const int wq   = t >> 6;
    const int lane = t & 63;
    const int quad = lane >> 4;
    const int l15  = lane & 15;
    const int m0   = blockIdx.x * 64;
    const int nb   = blockIdx.y;
    const float sc = (nb == 0) ? QS_LOG2E : 1.0f;

    #pragma unroll
    for (int i = 0; i < 8; ++i) {
        int s = t + i * 256;
        int row = s >> 5, c4 = s & 31;
        float4 v = *(const float4*)&X[(size_t)(m0 + row) * 128 + c4 * 4];
        uint2 pk;
        pk.x = f2b(v.x) | (f2b(v.y) << 16);
        pk.y = f2b(v.z) | (f2b(v.w) << 16);
        *(uint2*)&Xs[row * 136 + c4 * 4] = pk;
    }
    __syncthreads();

    floatx4 acc[8];
    #pragma unroll
    for (int nt = 0; nt < 8; ++nt)
        acc[nt] = (floatx4)(bias[nb * 128 + nt * 16 + l15]);

    #pragma unroll
    for (int kc = 0; kc < 4; ++kc) {
        bf16x8 af = *(const bf16x8*)&Xs[(wq * 16 + l15) * 136 + kc * 32 + quad * 8];
        #pragma unroll
        for (int nt = 0; nt < 8; ++nt) {
            bf16x8 bfr = *(const bf16x8*)&W[(size_t)(nb * 128 + nt * 16 + l15) * 128 + kc * 32 + quad * 8];
            acc[nt] = __builtin_amdgcn_mfma_f32_16x16x32_bf16(af, bfr, acc[nt], 0, 0, 0);
        }
    }

    #pragma unroll
    for (int r = 0; r < 4; ++r) {
        int m = m0 + wq * 16 + quad * 4 + r;
        #pragma unroll
        for (int nt = 0; nt < 8; ++nt)
            Y[(size_t)m * 384 + nb * 128 + nt * 16 + l15] = (ushort_t)f2b(acc[nt][r] * sc);
    }
}

// ---------------------------------------------------------------------------
// Projection GEMM, 64-row tiles, grid (512). bf16 in, fp32 out.
__global__ __launch_bounds__(256) void gemm_proj(
    const ushort_t* __restrict__ X, const ushort_t* __restrict__ W,
    const float* __restrict__ bias, float* __restrict__ Y)
{
    __shared__ ushort_t Xs[64 * 136];

    const int t    = threadIdx.x;
    const int wq   = t >> 6;
    const int lane = t & 63;
    const int quad = lane >> 4;
    const int l15  = lane & 15;
    const int m0   = blockIdx.x * 64;

    #pragma unroll
    for (int i = 0; i < 4; ++i) {
        int s = t + i * 256;
        int row = s >> 4, c8 = s & 15;
        *(int4*)&Xs[row * 136 + c8 * 8] = *(const int4*)&X[(size_t)(m0 + row) * 128 + c8 * 8];
    }
    __syncthreads();

    floatx4 acc[8];
    #pragma unroll
    for (int nt = 0; nt < 8; ++nt)
        acc[nt] = (floatx4)(bias[nt * 16 + l15]);

    #pragma unroll
    for (int kc = 0; kc < 4; ++kc) {
        bf16x8 af = *(const bf16x8*)&Xs[(wq * 16 + l15) * 136 + kc * 32 + quad * 8];
        #pragma unroll
        for (int nt = 0; nt < 8; ++nt) {
            bf16x8 bfr = *(const bf16x8*)&W[(size_t)(nt * 16 + l15) * 128 + kc * 32 + quad * 8];
            acc[nt] = __builtin_amdgcn_mfma_f32_16x16x32_bf16(af, bfr, acc[nt], 0, 0, 0);
        }
    }

    #pragma unroll
    for (int r = 0; r < 4; ++r) {
        int m = m0 + wq * 16 + quad * 4 + r;
        #pragma unroll
        for (int nt = 0; nt < 8; ++nt)
            Y[(size_t)m * 128 + nt * 16 + l15] = acc[nt][r];
    }
}

// ---------------------------------------------------------------------------
// Attention: block = (win, head); 4 INDEPENDENT waves, each 64 queries x all
// 1024 keys. No __syncthreads. Per-wave Vt (64-key chunk) + phased 32-key P.
// XCD swizzle: blockIdx.x&7 selects a 4x4-window spatial tile (one per XCD).
__global__ __launch_bounds__(256, 2) void halo_attn(
    const ushort_t* __restrict__ QKV,   // [32768][384] bf16 (Q pre-scaled)
    const ushort_t* __restrict__ biasf, // bf16 fragment bias (log2e domain)
    ushort_t* __restrict__ O)           // [32768][128] bf16
{
    __shared__ ushort_t P_lds[4 * 64 * PK];   // 20480 B, per-wave slices
    __shared__ ushort_t Vt_lds[4 * 32 * VK];  // 18432 B, per-wave slices

    const int t    = threadIdx.x;
    const int wave = t >> 6;
    const int lane = t & 63;
    const int quad = lane >> 4;
    const int l15  = lane & 15;

    // XCD-aware decode: tile id = x&7 (one per XCD), 16 windows per tile.
    const int x  = blockIdx.x;
    const int tt = x & 7;
    const int w  = x >> 3;
    const int b  = tt >> 2;
    const int wh = ((tt >> 1) & 1) * 4 + (w >> 2);
    const int ww = (tt & 1) * 4 + (w & 3);
    const int head = blockIdx.y;

    // Q B-fragments (persistent)
    bf16x8 qf[4];
    int qpix[4];
    #pragma unroll
    for (int qt = 0; qt < 4; ++qt) {
        int q_abs = wave * 64 + qt * 16 + l15;
        int gy = wh * 16 + (q_abs >> 4), gx = ww * 16 + (q_abs & 15);
        int pix = (b * 128 + gy) * 128 + gx;
        qpix[qt] = pix;
        qf[qt] = *(const bf16x8*)(QKV + (size_t)pix * 384 + head * 32 + quad * 8);
    }

    floatx4 Oa[2][4];
    #pragma unroll
    for (int dt = 0; dt < 2; ++dt)
        #pragma unroll
        for (int qt = 0; qt < 4; ++qt)
            Oa[dt][qt] = (floatx4)0.f;
    float l[4] = {0.f, 0.f, 0.f, 0.f};

    ushort_t* Pw  = P_lds  + wave * 64 * PK;
    ushort_t* Vtw = Vt_lds + wave * 32 * VK;

    for (int c = 0; c < 16; ++c) {
        // ---- V chunk -> LDS transposed (per-wave): lane owns one key ----
        {
            int keyv = c * 64 + lane;
            int ky = reflect_idx(wh * 16 + (keyv >> 5) - 8);
            int kx = reflect_idx(ww * 16 + (keyv & 31) - 8);
            int pixv = (b * 128 + ky) * 128 + kx;
            const int4* vp4 = (const int4*)(QKV + (size_t)pixv * 384 + 256 + head * 32);
            int4 vw0 = vp4[0], vw1 = vp4[1], vw2 = vp4[2], vw3 = vp4[3];
            const ushort_t* vs0 = (const ushort_t*)&vw0;
            const ushort_t* vs1 = (const ushort_t*)&vw1;
            const ushort_t* vs2 = (const ushort_t*)&vw2;
            const ushort_t* vs3 = (const ushort_t*)&vw3;
            #pragma unroll
            for (int d = 0; d < 8; ++d) {
                Vtw[(d +  0) * VK + lane] = vs0[d];
                Vtw[(d +  8) * VK + lane] = vs1[d];
                Vtw[(d + 16) * VK + lane] = vs2[d];
                Vtw[(d + 24) * VK + lane] = vs3[d];
            }
        }

        // ---- K A-fragments ----
        bf16x8 kf[4];
        #pragma unroll
        for (int kt = 0; kt < 4; ++kt) {
            int key = c * 64 + kt * 16 + l15;
            int ky = reflect_idx(wh * 16 + (key >> 5) - 8);
            int kx = reflect_idx(ww * 16 + (key & 31) - 8);
            int pixk = (b * 128 + ky) * 128 + kx;
            kf[kt] = *(const bf16x8*)(QKV + (size_t)pixk * 384 + 128 + head * 32 + quad * 8);
        }

        // ---- S init from bf16 bias fragments ----
        floatx4 S[4][4];
        #pragma unroll
        for (int kt = 0; kt < 4; ++kt) {
            int kt_abs = c * 4 + kt;
            #pragma unroll
            for (int qt = 0; qt < 4; ++qt) {
                int qt_abs = wave * 4 + qt;
                uint2 pk = *(const uint2*)(biasf +
                    ((((size_t)head * 64 + kt_abs) * 16 + qt_abs) * 64 + lane) * 4);
                S[kt][qt][0] = __uint_as_float(pk.x << 16);
                S[kt][qt][1] = __uint_as_float(pk.x & 0xffff0000u);
                S[kt][qt][2] = __uint_as_float(pk.y << 16);
                S[kt][qt][3] = __uint_as_float(pk.y & 0xffff0000u);
            }
        }
        #pragma unroll
        for (int kt = 0; kt < 4; ++kt)
            #pragma unroll
            for (int qt = 0; qt < 4; ++qt)
                S[kt][qt] = __builtin_amdgcn_mfma_f32_16x16x32_bf16(kf[kt], qf[qt], S[kt][qt], 0, 0, 0);

        // ---- exp2 + partial l ----
        #pragma unroll
        for (int qt = 0; qt < 4; ++qt) {
            float ls = 0.f;
            #pragma unroll
            for (int kt = 0; kt < 4; ++kt)
                #pragma unroll
                for (int r = 0; r < 4; ++r) {
                    float p = EXP2F(S[kt][qt][r]);
                    S[kt][qt][r] = p;
                    ls += p;
                }
            l[qt] += ls;
        }

        // ---- PV in two 32-key phases through the small per-wave P buffer ----
        #pragma unroll
        for (int ks = 0; ks < 2; ++ks) {
            #pragma unroll
            for (int qt = 0; qt < 4; ++qt)
                #pragma unroll
                for (int kh = 0; kh < 2; ++kh) {
                    int kt = ks * 2 + kh;
                    uint2 pk;
                    pk.x = __builtin_amdgcn_perm(__float_as_uint(S[kt][qt][1]),
                                                 __float_as_uint(S[kt][qt][0]), 0x07060302u);
                    pk.y = __builtin_amdgcn_perm(__float_as_uint(S[kt][qt][3]),
                                                 __float_as_uint(S[kt][qt][2]), 0x07060302u);
                    *(uint2*)&Pw[(qt * 16 + l15) * PK + kh * 16 + quad * 4] = pk;
                }
            bf16x8 vf[2];
            #pragma unroll
            for (int dt = 0; dt < 2; ++dt)
                vf[dt] = *(const bf16x8*)&Vtw[(dt * 16 + l15) * VK + ks * 32 + quad * 8];
            #pragma unroll
            for (int qt = 0; qt < 4; ++qt) {
                bf16x8 pf = *(const bf16x8*)&Pw[(qt * 16 + l15) * PK + quad * 8];
                #pragma unroll
                for (int dt = 0; dt < 2; ++dt)
                    Oa[dt][qt] = __builtin_amdgcn_mfma_f32_16x16x32_bf16(vf[dt], pf, Oa[dt][qt], 0, 0, 0);
            }
        }
    }

    // ---- epilogue: reduce l across quads, normalize, bf16 store ----
    #pragma unroll
    for (int qt = 0; qt < 4; ++qt) {
        float lq = l[qt];
        lq += __shfl_xor(lq, 16);
        lq += __shfl_xor(lq, 32);
        float inv = 1.0f / lq;
        #pragma unroll
        for (int dt = 0; dt < 2; ++dt) {
            uint2 pk;
            pk.x = f2b(Oa[dt][qt][0] * inv) | (f2b(Oa[dt][qt][1] * inv) << 16);
            pk.y = f2b(Oa[dt][qt][2] * inv) | (f2b(Oa[dt][qt][3] * inv) << 16);
            *(uint2*)(O + (size_t)qpix[qt] * 128 + head * 32 + dt * 16 + quad * 4) = pk;
        }
    }
}

// ---------------------------------------------------------------------------
extern "C" void kernel_launch(void* const* d_in, const int* in_sizes, int n_in,
                              void* d_out, int out_size, void* d_ws, size_t ws_size,
                              hipStream_t stream)
{
    const float* x          = (const float*)d_in[0];
    const float* Wq         = (const float*)d_in[1];
    const float* bq         = (const float*)d_in[2];
    const float* Wk         = (const float*)d_in[3];
    const float* bk         = (const float*)d_in[4];
    const float* Wv         = (const float*)d_in[5];
    const float* bv         = (const float*)d_in[6];
    const float* Wp         = (const float*)d_in[7];
    const float* bp         = (const float*)d_in[8];
    const float* bias_table = (const float*)d_in[9];
    float* out = (float*)d_out;

    char* ws = (char*)d_ws;
    ushort_t* Wqkv  = (ushort_t*)(ws);                    // 98304 B
    ushort_t* Wpb   = (ushort_t*)(ws + 98304);            // 32768 B
    float*    bqkv  = (float*)   (ws + 131072);           // 1536 B
    float*    bpb   = (float*)   (ws + 132608);           // 512 B
    ushort_t* QKV   = (ushort_t*)(ws + 133120);           // 25165824 B
    ushort_t* Ob    = (ushort_t*)(ws + 25298944);         // 8388608 B
    ushort_t* biasf = (ushort_t*)(ws + 33687552);         // 2097152 B

    prep<<<dim3(4353), dim3(256), 0, stream>>>(bias_table, Wq, Wk, Wv, Wp,
                                               bq, bk, bv, bp,
                                               biasf, Wqkv, Wpb, bqkv, bpb);
    gemm_qkv<<<dim3(512, 3), dim3(256), 0, stream>>>(x, Wqkv, bqkv, QKV);
    halo_attn<<<dim3(128, NHEADS), dim3(256), 0, stream>>>(QKV, biasf, Ob);
    gemm_proj<<<dim3(512), dim3(256), 0, stream>>>(Ob, Wpb, bpb, out);
}